// Round 2
// baseline (4312.364 us; speedup 1.0000x reference)
//
#include <hip/hip_runtime.h>

#define U_NUM 359347
#define I_NUM 292589
#define DDIM  64
#define NNZ_N 4000000
#define BATCH 32768
#define LAM_F 0.001f
#define ACC_SLOTS 2048

__device__ __forceinline__ float leaky(float x) { return x > 0.f ? x : 0.1f * x; }

// ---------------------------------------------------------------------------
// CSR build: histogram -> hierarchical exclusive scan -> scatter
// ---------------------------------------------------------------------------

__global__ __launch_bounds__(256) void hist_k(
    const int* __restrict__ rows, const int* __restrict__ cols,
    int* __restrict__ cnt_u, int* __restrict__ cnt_i, int nnz)
{
    int e = blockIdx.x * 256 + threadIdx.x;
    if (e >= nnz) return;
    atomicAdd(&cnt_u[rows[e]], 1);
    atomicAdd(&cnt_i[cols[e]], 1);
}

// in-place exclusive scan, 1024 elems/block (256 thr x 4)
__global__ __launch_bounds__(256) void scan1_k(int* __restrict__ a, int n, int* __restrict__ bsum)
{
    __shared__ int s[256];
    int t = threadIdx.x;
    int base = blockIdx.x * 1024 + t * 4;
    int v[4];
#pragma unroll
    for (int j = 0; j < 4; ++j) v[j] = (base + j < n) ? a[base + j] : 0;
    s[t] = v[0] + v[1] + v[2] + v[3];
    __syncthreads();
    for (int off = 1; off < 256; off <<= 1) {
        int x = (t >= off) ? s[t - off] : 0;
        __syncthreads();
        s[t] += x;
        __syncthreads();
    }
    if (t == 255) bsum[blockIdx.x] = s[255];
    int run = (t > 0) ? s[t - 1] : 0;
#pragma unroll
    for (int j = 0; j < 4; ++j) {
        if (base + j < n) a[base + j] = run;
        run += v[j];
    }
}

__global__ __launch_bounds__(512) void scan2_k(int* __restrict__ bsum, int nb)
{
    __shared__ int s[512];
    int t = threadIdx.x;
    int v = (t < nb) ? bsum[t] : 0;
    s[t] = v;
    __syncthreads();
    for (int off = 1; off < 512; off <<= 1) {
        int x = (t >= off) ? s[t - off] : 0;
        __syncthreads();
        s[t] += x;
        __syncthreads();
    }
    if (t < nb) bsum[t] = s[t] - v;   // exclusive
}

__global__ __launch_bounds__(256) void scan3_k(int* __restrict__ a, int n, const int* __restrict__ bsum)
{
    int add = bsum[blockIdx.x];
    int base = blockIdx.x * 1024 + threadIdx.x * 4;
#pragma unroll
    for (int j = 0; j < 4; ++j)
        if (base + j < n) a[base + j] += add;
}

__global__ __launch_bounds__(256) void scatter_k(
    const int* __restrict__ rows, const int* __restrict__ cols,
    const float* __restrict__ uv, const float* __restrict__ iv,
    const int* __restrict__ ptr_u, const int* __restrict__ ptr_i,
    int* __restrict__ cur_u, int* __restrict__ cur_i,
    int* __restrict__ cu_col, float* __restrict__ cu_val,
    int* __restrict__ ci_row, float* __restrict__ ci_val, int nnz)
{
    int e = blockIdx.x * 256 + threadIdx.x;
    if (e >= nnz) return;
    int r = rows[e], c = cols[e];
    int pu = ptr_u[r] + atomicAdd(&cur_u[r], 1);
    cu_col[pu] = c;
    cu_val[pu] = uv[e];
    int pi = ptr_i[c] + atomicAdd(&cur_i[c], 1);
    ci_row[pi] = r;
    ci_val[pi] = iv[e];
}

// ---------------------------------------------------------------------------
// CSR SpMM, one wave per row (lane = dim), residual+ReLU fused in epilogue.
// FUSE_L2: also accumulate sum((w0*embed + w1*base + w2*out)^2) into accArr.
// ---------------------------------------------------------------------------
template <int FUSE_L2>
__global__ __launch_bounds__(256) void spmm_csr_k(
    const int* __restrict__ ptr, const int* __restrict__ idx, const float* __restrict__ val,
    const float* __restrict__ x, const float* __restrict__ base,
    const float* __restrict__ deg, float* __restrict__ out, int nrows,
    const float* __restrict__ embed, const float* __restrict__ add_w,
    float* __restrict__ accArr)
{
    int wv = threadIdx.x >> 6, lane = threadIdx.x & 63;
    int r = blockIdx.x * 4 + wv;
    __shared__ float ssum[4];
    if (r < nrows) {
        int s0 = ptr[r], e0 = ptr[r + 1];
        float acc = 0.f;
        for (int k = s0; k < e0;) {
            int cnt = min(64, e0 - k);
            int ci = (lane < cnt) ? idx[k + lane] : 0;
            float vi = (lane < cnt) ? val[k + lane] : 0.f;
            int j = 0;
            for (; j + 4 <= cnt; j += 4) {
                int   c0 = __shfl(ci, j),     c1 = __shfl(ci, j + 1);
                int   c2 = __shfl(ci, j + 2), c3 = __shfl(ci, j + 3);
                float v0 = __shfl(vi, j),     v1 = __shfl(vi, j + 1);
                float v2 = __shfl(vi, j + 2), v3 = __shfl(vi, j + 3);
                float x0 = x[(size_t)c0 * DDIM + lane];
                float x1 = x[(size_t)c1 * DDIM + lane];
                float x2 = x[(size_t)c2 * DDIM + lane];
                float x3 = x[(size_t)c3 * DDIM + lane];
                acc = fmaf(v0, x0, acc);
                acc = fmaf(v1, x1, acc);
                acc = fmaf(v2, x2, acc);
                acc = fmaf(v3, x3, acc);
            }
            for (; j < cnt; ++j) {
                int   cj = __shfl(ci, j);
                float vj = __shfl(vi, j);
                acc = fmaf(vj, x[(size_t)cj * DDIM + lane], acc);
            }
            k += cnt;
        }
        float bb = base[(size_t)r * DDIM + lane];
        float o = fmaxf(fmaf(bb, deg[r], acc), 0.f);
        out[(size_t)r * DDIM + lane] = o;
        if (FUSE_L2) {
            float g = fmaf(add_w[0], embed[(size_t)r * DDIM + lane],
                           fmaf(add_w[1], bb, add_w[2] * o));
            float sq = g * g;
            for (int off = 32; off; off >>= 1) sq += __shfl_down(sq, off);
            if (lane == 0) ssum[wv] = sq;
        }
    } else if (FUSE_L2) {
        if (lane == 0) ssum[wv] = 0.f;
    }
    if (FUSE_L2) {
        __syncthreads();
        if (threadIdx.x == 0)
            atomicAdd(&accArr[blockIdx.x & (ACC_SLOTS - 1)],
                      ssum[0] + ssum[1] + ssum[2] + ssum[3]);
    }
}

// ---------------------------------------------------------------------------
// Fallback-path kernels (round-1 atomic version, used only if ws too small)
// ---------------------------------------------------------------------------

__global__ __launch_bounds__(256) void spmm_atomic_k(
    const int* __restrict__ rows, const int* __restrict__ cols,
    const float* __restrict__ vals, const float* __restrict__ x,
    float* __restrict__ out, int nnz)
{
    int e = blockIdx.x * 4 + (threadIdx.x >> 6);
    if (e >= nnz) return;
    int lane = threadIdx.x & 63;
    int r = rows[e], c = cols[e];
    float v = vals[e];
    atomicAdd(&out[(size_t)r * DDIM + lane], v * x[(size_t)c * DDIM + lane]);
}

__global__ __launch_bounds__(256) void relu_resid_k(
    float* __restrict__ acc, const float* __restrict__ base,
    const float* __restrict__ deg, size_t n4)
{
    size_t i = (size_t)blockIdx.x * 256 + threadIdx.x;
    if (i >= n4) return;
    size_t row = i >> 4;
    float d = deg[row];
    float4 a = reinterpret_cast<float4*>(acc)[i];
    const float4 b = reinterpret_cast<const float4*>(base)[i];
    a.x = fmaxf(fmaf(b.x, d, a.x), 0.f);
    a.y = fmaxf(fmaf(b.y, d, a.y), 0.f);
    a.z = fmaxf(fmaf(b.z, d, a.z), 0.f);
    a.w = fmaxf(fmaf(b.w, d, a.w), 0.f);
    reinterpret_cast<float4*>(acc)[i] = a;
}

__global__ __launch_bounds__(256) void l2_reduce_k(
    const float* __restrict__ e, const float* __restrict__ g1,
    const float* __restrict__ g2, const float* __restrict__ add_w,
    size_t n, float* __restrict__ acc)
{
    float w0 = add_w[0], w1 = add_w[1], w2 = add_w[2];
    float s = 0.f;
    size_t stride = (size_t)gridDim.x * 256;
    for (size_t i = (size_t)blockIdx.x * 256 + threadIdx.x; i < n; i += stride) {
        float g = fmaf(w0, e[i], fmaf(w1, g1[i], w2 * g2[i]));
        s = fmaf(g, g, s);
    }
    for (int off = 32; off; off >>= 1) s += __shfl_down(s, off);
    __shared__ float wsum[4];
    int lane = threadIdx.x & 63, wv = threadIdx.x >> 6;
    if (lane == 0) wsum[wv] = s;
    __syncthreads();
    if (threadIdx.x == 0)
        atomicAdd(acc, wsum[0] + wsum[1] + wsum[2] + wsum[3]);
}

// ---------------------------------------------------------------------------
// Batch MLP (one wave per sample) and finalize
// ---------------------------------------------------------------------------

__global__ __launch_bounds__(256) void batch_mlp_k(
    const int* __restrict__ user0, const int* __restrict__ item0,
    const float* __restrict__ eu, const float* __restrict__ g1u, const float* __restrict__ g2u,
    const float* __restrict__ ei, const float* __restrict__ g1i, const float* __restrict__ g2i,
    const float* __restrict__ add_w,
    const float* __restrict__ fw1, const float* __restrict__ fb1,
    const float* __restrict__ fw2, const float* __restrict__ fb2,
    const float* __restrict__ ub, const float* __restrict__ ib,
    const float* __restrict__ avg, const float* __restrict__ ratings,
    float* __restrict__ sse_acc)
{
    __shared__ float s_x[4][64];
    __shared__ float s_h[4][128];
    int wv = threadIdx.x >> 6, lane = threadIdx.x & 63;
    int b = blockIdx.x * 4 + wv;
    float w0 = add_w[0], w1 = add_w[1], w2 = add_w[2];
    float sv0 = 0.f, sv1 = 0.f;
#pragma unroll
    for (int side = 0; side < 2; ++side) {
        int idx = side ? item0[b] : user0[b];
        const float* E  = side ? ei  : eu;
        const float* G1 = side ? g1i : g1u;
        const float* G2 = side ? g2i : g2u;
        size_t base = (size_t)idx * 64;
        s_x[wv][lane] = fmaf(w0, E[base + lane], fmaf(w1, G1[base + lane], w2 * G2[base + lane]));
        __syncthreads();
        float h0 = fb1[lane], h1 = fb1[lane + 64];
#pragma unroll 8
        for (int d = 0; d < 64; ++d) {
            float xv = s_x[wv][d];
            h0 = fmaf(fw1[lane * 64 + d], xv, h0);
            h1 = fmaf(fw1[(lane + 64) * 64 + d], xv, h1);
        }
        s_h[wv][lane]      = leaky(h0);
        s_h[wv][lane + 64] = leaky(h1);
        __syncthreads();
        float o = fb2[lane];
#pragma unroll 8
        for (int k = 0; k < 128; ++k)
            o = fmaf(fw2[lane * 128 + k], s_h[wv][k], o);
        o = leaky(o);
        if (side == 0) sv0 = o; else sv1 = o;
        __syncthreads();
    }
    float p = sv0 * sv1;
    for (int off = 32; off; off >>= 1) p += __shfl_down(p, off);
    __shared__ float s_p[4];
    if (lane == 0) {
        float pred = p + ub[user0[b]] + ib[item0[b]] + avg[0];
        float diff = pred - ratings[b];
        s_p[wv] = diff * diff;
    }
    __syncthreads();
    if (threadIdx.x == 0)
        atomicAdd(sse_acc, s_p[0] + s_p[1] + s_p[2] + s_p[3]);
}

__global__ __launch_bounds__(256) void finalize2_k(
    const float* __restrict__ accU, const float* __restrict__ accI,
    const float* __restrict__ sse, float* __restrict__ out)
{
    int t = threadIdx.x;
    float su = 0.f, si = 0.f;
    for (int i = t; i < ACC_SLOTS; i += 256) { su += accU[i]; si += accI[i]; }
    for (int off = 32; off; off >>= 1) {
        su += __shfl_down(su, off);
        si += __shfl_down(si, off);
    }
    __shared__ float s[8];
    int wv = t >> 6, lane = t & 63;
    if (lane == 0) { s[wv] = su; s[wv + 4] = si; }
    __syncthreads();
    if (t == 0) {
        float SU = s[0] + s[1] + s[2] + s[3];
        float SI = s[4] + s[5] + s[6] + s[7];
        out[0] = sse[0] / (float)BATCH
               + LAM_F * (SU / (float)((double)U_NUM * 64.0))
               + LAM_F * (SI / (float)((double)I_NUM * 64.0));
    }
}

__global__ void finalize_k(const float* __restrict__ acc, float* __restrict__ out)
{
    out[0] = acc[2] / (float)BATCH
           + LAM_F * (acc[0] / (float)((double)U_NUM * 64.0))
           + LAM_F * (acc[1] / (float)((double)I_NUM * 64.0));
}

// ---------------------------------------------------------------------------

extern "C" void kernel_launch(void* const* d_in, const int* in_sizes, int n_in,
                              void* d_out, int out_size, void* d_ws, size_t ws_size,
                              hipStream_t stream)
{
    const int*   ui_rows = (const int*)d_in[0];
    const int*   ui_cols = (const int*)d_in[1];
    const float* ui_vals = (const float*)d_in[2];
    const float* iu_vals = (const float*)d_in[3];
    const float* d_i     = (const float*)d_in[4];
    const float* d_j     = (const float*)d_in[5];
    const float* eu      = (const float*)d_in[6];
    const float* ei      = (const float*)d_in[7];
    const float* add_w   = (const float*)d_in[8];
    const float* fw1     = (const float*)d_in[9];
    const float* fb1     = (const float*)d_in[10];
    const float* fw2     = (const float*)d_in[11];
    const float* fb2     = (const float*)d_in[12];
    const float* ub      = (const float*)d_in[13];
    const float* ib      = (const float*)d_in[14];
    const float* avg     = (const float*)d_in[15];
    const int*   user0   = (const int*)d_in[16];
    const int*   item0   = (const int*)d_in[17];
    const float* ratings = (const float*)d_in[18];

    const size_t U64 = (size_t)U_NUM * DDIM;
    const size_t I64 = (size_t)I_NUM * DDIM;

    // dense intermediates
    float* g1u = (float*)d_ws;
    float* g2u = g1u + U64;
    float* g1i = g2u + U64;
    float* g2i = g1i + I64;

    // CSR storage
    float* cu_val = g2i + I64;              // NNZ floats
    int*   cu_col = (int*)(cu_val + NNZ_N); // NNZ ints
    float* ci_val = (float*)(cu_col + NNZ_N);
    int*   ci_row = (int*)(ci_val + NNZ_N);

    // meta region (single memset): ptr_u | ptr_i | cur_u | cur_i | bsumU | bsumI | accU | accI | sse
    int* meta   = (int*)(ci_row + NNZ_N);
    int* ptr_u  = meta;                    // U+1
    int* ptr_i  = ptr_u + (U_NUM + 1);     // I+1
    int* cur_u  = ptr_i + (I_NUM + 1);     // U
    int* cur_i  = cur_u + U_NUM;           // I
    int* bsumU  = cur_i + I_NUM;           // 512
    int* bsumI  = bsumU + 512;             // 512
    float* accU = (float*)(bsumI + 512);   // ACC_SLOTS
    float* accI = accU + ACC_SLOTS;        // ACC_SLOTS
    float* sse  = accI + ACC_SLOTS;        // 4
    size_t meta_ints = (size_t)(U_NUM + 1) + (I_NUM + 1) + U_NUM + I_NUM
                     + 1024 + 2 * ACC_SLOTS + 4;
    size_t needed = ((char*)(meta + meta_ints)) - (char*)d_ws;

    dim3 blk(256);

    if (ws_size >= needed) {
        // ---- CSR path ----
        hipMemsetAsync(meta, 0, meta_ints * sizeof(int), stream);

        int eg = (NNZ_N + 255) / 256;
        hist_k<<<eg, blk, 0, stream>>>(ui_rows, ui_cols, ptr_u, ptr_i, NNZ_N);

        int nU = U_NUM + 1, nI = I_NUM + 1;
        int nbU = (nU + 1023) / 1024, nbI = (nI + 1023) / 1024;
        scan1_k<<<nbU, blk, 0, stream>>>(ptr_u, nU, bsumU);
        scan2_k<<<1, 512, 0, stream>>>(bsumU, nbU);
        scan3_k<<<nbU, blk, 0, stream>>>(ptr_u, nU, bsumU);
        scan1_k<<<nbI, blk, 0, stream>>>(ptr_i, nI, bsumI);
        scan2_k<<<1, 512, 0, stream>>>(bsumI, nbI);
        scan3_k<<<nbI, blk, 0, stream>>>(ptr_i, nI, bsumI);

        scatter_k<<<eg, blk, 0, stream>>>(ui_rows, ui_cols, ui_vals, iu_vals,
                                          ptr_u, ptr_i, cur_u, cur_i,
                                          cu_col, cu_val, ci_row, ci_val, NNZ_N);

        int gu = (U_NUM + 3) / 4, gi = (I_NUM + 3) / 4;
        // layer 1 (no L2 fusion)
        spmm_csr_k<0><<<gu, blk, 0, stream>>>(ptr_u, cu_col, cu_val, ei, eu, d_i,
                                              g1u, U_NUM, nullptr, nullptr, nullptr);
        spmm_csr_k<0><<<gi, blk, 0, stream>>>(ptr_i, ci_row, ci_val, eu, ei, d_j,
                                              g1i, I_NUM, nullptr, nullptr, nullptr);
        // layer 2 (fused L2 mean-square partials)
        spmm_csr_k<1><<<gu, blk, 0, stream>>>(ptr_u, cu_col, cu_val, g1i, g1u, d_i,
                                              g2u, U_NUM, eu, add_w, accU);
        spmm_csr_k<1><<<gi, blk, 0, stream>>>(ptr_i, ci_row, ci_val, g1u, g1i, d_j,
                                              g2i, I_NUM, ei, add_w, accI);

        batch_mlp_k<<<BATCH / 4, blk, 0, stream>>>(user0, item0, eu, g1u, g2u, ei, g1i, g2i,
                                                   add_w, fw1, fb1, fw2, fb2, ub, ib, avg,
                                                   ratings, sse);
        finalize2_k<<<1, blk, 0, stream>>>(accU, accI, sse, (float*)d_out);
    } else {
        // ---- fallback: round-1 atomic path ----
        float* acc = cu_val;  // reuse first scratch after dense buffers
        hipMemsetAsync(d_ws, 0, (2 * U64 + 2 * I64 + 8) * sizeof(float), stream);

        int spmm_grid = (NNZ_N + 3) / 4;
        spmm_atomic_k<<<spmm_grid, blk, 0, stream>>>(ui_rows, ui_cols, ui_vals, ei, g1u, NNZ_N);
        spmm_atomic_k<<<spmm_grid, blk, 0, stream>>>(ui_cols, ui_rows, iu_vals, eu, g1i, NNZ_N);
        relu_resid_k<<<(U_NUM * 16 + 255) / 256, blk, 0, stream>>>(g1u, eu, d_i, (size_t)U_NUM * 16);
        relu_resid_k<<<(I_NUM * 16 + 255) / 256, blk, 0, stream>>>(g1i, ei, d_j, (size_t)I_NUM * 16);
        spmm_atomic_k<<<spmm_grid, blk, 0, stream>>>(ui_rows, ui_cols, ui_vals, g1i, g2u, NNZ_N);
        spmm_atomic_k<<<spmm_grid, blk, 0, stream>>>(ui_cols, ui_rows, iu_vals, g1u, g2i, NNZ_N);
        relu_resid_k<<<(U_NUM * 16 + 255) / 256, blk, 0, stream>>>(g2u, g1u, d_i, (size_t)U_NUM * 16);
        relu_resid_k<<<(I_NUM * 16 + 255) / 256, blk, 0, stream>>>(g2i, g1i, d_j, (size_t)I_NUM * 16);
        l2_reduce_k<<<2048, blk, 0, stream>>>(eu, g1u, g2u, add_w, U64, acc + 0);
        l2_reduce_k<<<2048, blk, 0, stream>>>(ei, g1i, g2i, add_w, I64, acc + 1);
        batch_mlp_k<<<BATCH / 4, blk, 0, stream>>>(user0, item0, eu, g1u, g2u, ei, g1i, g2i,
                                                   add_w, fw1, fb1, fw2, fb2, ub, ib, avg,
                                                   ratings, acc + 2);
        finalize_k<<<1, 1, 0, stream>>>(acc, (float*)d_out);
    }
}

// Round 3
// 2275.495 us; speedup vs baseline: 1.8951x; 1.8951x over previous
//
#include <hip/hip_runtime.h>

#define U_NUM 359347
#define I_NUM 292589
#define DDIM  64
#define NNZ_N 4000000
#define BATCH 32768
#define LAM_F 0.001f
#define ACC_SLOTS 2048

__device__ __forceinline__ float leaky(float x) { return x > 0.f ? x : 0.1f * x; }

// ---------------------------------------------------------------------------
// CSR build: histogram -> hierarchical exclusive scan -> scatter
// ---------------------------------------------------------------------------

__global__ __launch_bounds__(256) void hist_k(
    const int* __restrict__ rows, const int* __restrict__ cols,
    int* __restrict__ cnt_u, int* __restrict__ cnt_i, int nnz)
{
    int e = blockIdx.x * 256 + threadIdx.x;
    if (e >= nnz) return;
    atomicAdd(&cnt_u[rows[e]], 1);
    atomicAdd(&cnt_i[cols[e]], 1);
}

// in-place exclusive scan, 1024 elems/block (256 thr x 4)
__global__ __launch_bounds__(256) void scan1_k(int* __restrict__ a, int n, int* __restrict__ bsum)
{
    __shared__ int s[256];
    int t = threadIdx.x;
    int base = blockIdx.x * 1024 + t * 4;
    int v[4];
#pragma unroll
    for (int j = 0; j < 4; ++j) v[j] = (base + j < n) ? a[base + j] : 0;
    s[t] = v[0] + v[1] + v[2] + v[3];
    __syncthreads();
    for (int off = 1; off < 256; off <<= 1) {
        int x = (t >= off) ? s[t - off] : 0;
        __syncthreads();
        s[t] += x;
        __syncthreads();
    }
    if (t == 255) bsum[blockIdx.x] = s[255];
    int run = (t > 0) ? s[t - 1] : 0;
#pragma unroll
    for (int j = 0; j < 4; ++j) {
        if (base + j < n) a[base + j] = run;
        run += v[j];
    }
}

__global__ __launch_bounds__(512) void scan2_k(int* __restrict__ bsum, int nb)
{
    __shared__ int s[512];
    int t = threadIdx.x;
    int v = (t < nb) ? bsum[t] : 0;
    s[t] = v;
    __syncthreads();
    for (int off = 1; off < 512; off <<= 1) {
        int x = (t >= off) ? s[t - off] : 0;
        __syncthreads();
        s[t] += x;
        __syncthreads();
    }
    if (t < nb) bsum[t] = s[t] - v;   // exclusive
}

__global__ __launch_bounds__(256) void scan3_k(int* __restrict__ a, int n, const int* __restrict__ bsum)
{
    int add = bsum[blockIdx.x];
    int base = blockIdx.x * 1024 + threadIdx.x * 4;
#pragma unroll
    for (int j = 0; j < 4; ++j)
        if (base + j < n) a[base + j] += add;
}

__global__ __launch_bounds__(256) void scatter_k(
    const int* __restrict__ rows, const int* __restrict__ cols,
    const float* __restrict__ uv, const float* __restrict__ iv,
    const int* __restrict__ ptr_u, const int* __restrict__ ptr_i,
    int* __restrict__ cur_u, int* __restrict__ cur_i,
    int* __restrict__ cu_col, float* __restrict__ cu_val,
    int* __restrict__ ci_row, float* __restrict__ ci_val, int nnz)
{
    int e = blockIdx.x * 256 + threadIdx.x;
    if (e >= nnz) return;
    int r = rows[e], c = cols[e];
    int pu = ptr_u[r] + atomicAdd(&cur_u[r], 1);
    cu_col[pu] = c;
    cu_val[pu] = uv[e];
    int pi = ptr_i[c] + atomicAdd(&cur_i[c], 1);
    ci_row[pi] = r;
    ci_val[pi] = iv[e];
}

// ---------------------------------------------------------------------------
// CSR SpMM, one wave per row (lane = dim).
// MODE 0: out = relu(A@x + base*deg)                        (layer 1)
// MODE 1: g2 = relu(A@x + base*deg);
//         out = w0*embed + w1*base + w2*g2  (combined gcn);
//         accumulate sum(out^2) into accArr slots.           (layer 2)
// NOTE: base/out may alias (in-place combine) -> no __restrict__ on them.
// ---------------------------------------------------------------------------
template <int MODE>
__global__ __launch_bounds__(256) void spmm_csr_k(
    const int* __restrict__ ptr, const int* __restrict__ idx, const float* __restrict__ val,
    const float* __restrict__ x, const float* base,
    const float* __restrict__ deg, float* out, int nrows,
    const float* __restrict__ embed, const float* __restrict__ add_w,
    float* __restrict__ accArr)
{
    int wv = threadIdx.x >> 6, lane = threadIdx.x & 63;
    int r = blockIdx.x * 4 + wv;
    __shared__ float ssum[4];
    if (r < nrows) {
        int s0 = __builtin_amdgcn_readfirstlane(ptr[r]);
        int e0 = __builtin_amdgcn_readfirstlane(ptr[r + 1]);
        float a0 = 0.f, a1 = 0.f, a2 = 0.f, a3 = 0.f;
        int k = s0;
        for (; k + 4 <= e0; k += 4) {
            int   c0 = idx[k],     c1 = idx[k + 1], c2 = idx[k + 2], c3 = idx[k + 3];
            float v0 = val[k],     v1 = val[k + 1], v2 = val[k + 2], v3 = val[k + 3];
            a0 = fmaf(v0, x[(size_t)c0 * DDIM + lane], a0);
            a1 = fmaf(v1, x[(size_t)c1 * DDIM + lane], a1);
            a2 = fmaf(v2, x[(size_t)c2 * DDIM + lane], a2);
            a3 = fmaf(v3, x[(size_t)c3 * DDIM + lane], a3);
        }
        for (; k < e0; ++k)
            a0 = fmaf(val[k], x[(size_t)idx[k] * DDIM + lane], a0);
        float acc = (a0 + a1) + (a2 + a3);
        float bb = base[(size_t)r * DDIM + lane];
        float o = fmaxf(fmaf(bb, deg[r], acc), 0.f);
        if (MODE == 0) {
            out[(size_t)r * DDIM + lane] = o;
        } else {
            float g = fmaf(add_w[0], embed[(size_t)r * DDIM + lane],
                           fmaf(add_w[1], bb, add_w[2] * o));
            out[(size_t)r * DDIM + lane] = g;
            float sq = g * g;
            for (int off = 32; off; off >>= 1) sq += __shfl_down(sq, off);
            if (lane == 0) ssum[wv] = sq;
        }
    } else if (MODE == 1) {
        if (lane == 0) ssum[wv] = 0.f;
    }
    if (MODE == 1) {
        __syncthreads();
        if (threadIdx.x == 0)
            atomicAdd(&accArr[blockIdx.x & (ACC_SLOTS - 1)],
                      ssum[0] + ssum[1] + ssum[2] + ssum[3]);
    }
}

// ---------------------------------------------------------------------------
// Batch MLP v2: LDS-staged transposed weights, 1 wave = 1 sample (both sides
// at once), grid-stride over samples. Inputs are pre-combined gcn rows.
// ---------------------------------------------------------------------------
__global__ __launch_bounds__(256) void batch_mlp2_k(
    const int* __restrict__ user0, const int* __restrict__ item0,
    const float* __restrict__ gcnU, const float* __restrict__ gcnI,
    const float* __restrict__ fw1, const float* __restrict__ fb1,
    const float* __restrict__ fw2, const float* __restrict__ fb2,
    const float* __restrict__ ub, const float* __restrict__ ib,
    const float* __restrict__ avg, const float* __restrict__ ratings,
    float* __restrict__ sse_acc)
{
    __shared__ float2 w1p[64][64];   // [d][o] -> (fw1[o][d], fw1[o+64][d])  32KB
    __shared__ float  w2T[128][64];  // [k][o] -> fw2[o][k]                  32KB
    for (int i = threadIdx.x; i < 8192; i += 256) {
        int o = i >> 6, d = i & 63;          // fw1 row o, col d
        float v = fw1[i];
        if (o < 64) w1p[d][o].x = v; else w1p[d][o - 64].y = v;
        int oo = i >> 7, kk = i & 127;       // fw2 row oo, col kk
        w2T[kk][oo] = fw2[i];
    }
    __syncthreads();
    int wv = threadIdx.x >> 6, lane = threadIdx.x & 63;
    float b1a = fb1[lane], b1b = fb1[lane + 64], b2 = fb2[lane];
    float avgv = avg[0];
    float lsum = 0.f;
    for (int b = blockIdx.x * 4 + wv; b < BATCH; b += gridDim.x * 4) {
        int uidx = user0[b], iidx = item0[b];
        float xu = gcnU[(size_t)uidx * DDIM + lane];
        float xi = gcnI[(size_t)iidx * DDIM + lane];
        float hu0 = b1a, hu1 = b1b, hi0 = b1a, hi1 = b1b;
#pragma unroll
        for (int d = 0; d < 64; ++d) {
            float2 w = w1p[d][lane];
            float xud = __shfl(xu, d);
            float xid = __shfl(xi, d);
            hu0 = fmaf(w.x, xud, hu0);
            hu1 = fmaf(w.y, xud, hu1);
            hi0 = fmaf(w.x, xid, hi0);
            hi1 = fmaf(w.y, xid, hi1);
        }
        hu0 = leaky(hu0); hu1 = leaky(hu1);
        hi0 = leaky(hi0); hi1 = leaky(hi1);
        float ou = b2, oi = b2;
#pragma unroll
        for (int kk = 0; kk < 64; ++kk) {
            float w = w2T[kk][lane];
            ou = fmaf(w, __shfl(hu0, kk), ou);
            oi = fmaf(w, __shfl(hi0, kk), oi);
        }
#pragma unroll
        for (int kk = 0; kk < 64; ++kk) {
            float w = w2T[kk + 64][lane];
            ou = fmaf(w, __shfl(hu1, kk), ou);
            oi = fmaf(w, __shfl(hi1, kk), oi);
        }
        ou = leaky(ou); oi = leaky(oi);
        float p = ou * oi;
        for (int off = 32; off; off >>= 1) p += __shfl_down(p, off);
        if (lane == 0) {
            float pred = p + ub[uidx] + ib[iidx] + avgv;
            float diff = pred - ratings[b];
            lsum = fmaf(diff, diff, lsum);
        }
    }
    __shared__ float s_p[4];
    if (lane == 0) s_p[wv] = lsum;
    __syncthreads();
    if (threadIdx.x == 0)
        atomicAdd(sse_acc, s_p[0] + s_p[1] + s_p[2] + s_p[3]);
}

__global__ __launch_bounds__(256) void finalize2_k(
    const float* __restrict__ accU, const float* __restrict__ accI,
    const float* __restrict__ sse, float* __restrict__ out)
{
    int t = threadIdx.x;
    float su = 0.f, si = 0.f;
    for (int i = t; i < ACC_SLOTS; i += 256) { su += accU[i]; si += accI[i]; }
    for (int off = 32; off; off >>= 1) {
        su += __shfl_down(su, off);
        si += __shfl_down(si, off);
    }
    __shared__ float s[8];
    int wv = t >> 6, lane = t & 63;
    if (lane == 0) { s[wv] = su; s[wv + 4] = si; }
    __syncthreads();
    if (t == 0) {
        float SU = s[0] + s[1] + s[2] + s[3];
        float SI = s[4] + s[5] + s[6] + s[7];
        out[0] = sse[0] / (float)BATCH
               + LAM_F * (SU / (float)((double)U_NUM * 64.0))
               + LAM_F * (SI / (float)((double)I_NUM * 64.0));
    }
}

// ---------------------------------------------------------------------------
// Fallback-path kernels (round-1 atomic version, used only if ws too small)
// ---------------------------------------------------------------------------

__global__ __launch_bounds__(256) void spmm_atomic_k(
    const int* __restrict__ rows, const int* __restrict__ cols,
    const float* __restrict__ vals, const float* __restrict__ x,
    float* __restrict__ out, int nnz)
{
    int e = blockIdx.x * 4 + (threadIdx.x >> 6);
    if (e >= nnz) return;
    int lane = threadIdx.x & 63;
    int r = rows[e], c = cols[e];
    float v = vals[e];
    atomicAdd(&out[(size_t)r * DDIM + lane], v * x[(size_t)c * DDIM + lane]);
}

__global__ __launch_bounds__(256) void relu_resid_k(
    float* __restrict__ acc, const float* __restrict__ base,
    const float* __restrict__ deg, size_t n4)
{
    size_t i = (size_t)blockIdx.x * 256 + threadIdx.x;
    if (i >= n4) return;
    size_t row = i >> 4;
    float d = deg[row];
    float4 a = reinterpret_cast<float4*>(acc)[i];
    const float4 b = reinterpret_cast<const float4*>(base)[i];
    a.x = fmaxf(fmaf(b.x, d, a.x), 0.f);
    a.y = fmaxf(fmaf(b.y, d, a.y), 0.f);
    a.z = fmaxf(fmaf(b.z, d, a.z), 0.f);
    a.w = fmaxf(fmaf(b.w, d, a.w), 0.f);
    reinterpret_cast<float4*>(acc)[i] = a;
}

__global__ __launch_bounds__(256) void l2_reduce_k(
    const float* __restrict__ e, const float* __restrict__ g1,
    const float* __restrict__ g2, const float* __restrict__ add_w,
    size_t n, float* __restrict__ acc)
{
    float w0 = add_w[0], w1 = add_w[1], w2 = add_w[2];
    float s = 0.f;
    size_t stride = (size_t)gridDim.x * 256;
    for (size_t i = (size_t)blockIdx.x * 256 + threadIdx.x; i < n; i += stride) {
        float g = fmaf(w0, e[i], fmaf(w1, g1[i], w2 * g2[i]));
        s = fmaf(g, g, s);
    }
    for (int off = 32; off; off >>= 1) s += __shfl_down(s, off);
    __shared__ float wsum[4];
    int lane = threadIdx.x & 63, wv = threadIdx.x >> 6;
    if (lane == 0) wsum[wv] = s;
    __syncthreads();
    if (threadIdx.x == 0)
        atomicAdd(acc, wsum[0] + wsum[1] + wsum[2] + wsum[3]);
}

__global__ __launch_bounds__(256) void batch_mlp_k(
    const int* __restrict__ user0, const int* __restrict__ item0,
    const float* __restrict__ eu, const float* __restrict__ g1u, const float* __restrict__ g2u,
    const float* __restrict__ ei, const float* __restrict__ g1i, const float* __restrict__ g2i,
    const float* __restrict__ add_w,
    const float* __restrict__ fw1, const float* __restrict__ fb1,
    const float* __restrict__ fw2, const float* __restrict__ fb2,
    const float* __restrict__ ub, const float* __restrict__ ib,
    const float* __restrict__ avg, const float* __restrict__ ratings,
    float* __restrict__ sse_acc)
{
    __shared__ float s_x[4][64];
    __shared__ float s_h[4][128];
    int wv = threadIdx.x >> 6, lane = threadIdx.x & 63;
    int b = blockIdx.x * 4 + wv;
    float w0 = add_w[0], w1 = add_w[1], w2 = add_w[2];
    float sv0 = 0.f, sv1 = 0.f;
#pragma unroll
    for (int side = 0; side < 2; ++side) {
        int idx = side ? item0[b] : user0[b];
        const float* E  = side ? ei  : eu;
        const float* G1 = side ? g1i : g1u;
        const float* G2 = side ? g2i : g2u;
        size_t base = (size_t)idx * 64;
        s_x[wv][lane] = fmaf(w0, E[base + lane], fmaf(w1, G1[base + lane], w2 * G2[base + lane]));
        __syncthreads();
        float h0 = fb1[lane], h1 = fb1[lane + 64];
#pragma unroll 8
        for (int d = 0; d < 64; ++d) {
            float xv = s_x[wv][d];
            h0 = fmaf(fw1[lane * 64 + d], xv, h0);
            h1 = fmaf(fw1[(lane + 64) * 64 + d], xv, h1);
        }
        s_h[wv][lane]      = leaky(h0);
        s_h[wv][lane + 64] = leaky(h1);
        __syncthreads();
        float o = fb2[lane];
#pragma unroll 8
        for (int k = 0; k < 128; ++k)
            o = fmaf(fw2[lane * 128 + k], s_h[wv][k], o);
        o = leaky(o);
        if (side == 0) sv0 = o; else sv1 = o;
        __syncthreads();
    }
    float p = sv0 * sv1;
    for (int off = 32; off; off >>= 1) p += __shfl_down(p, off);
    __shared__ float s_p[4];
    if (lane == 0) {
        float pred = p + ub[user0[b]] + ib[item0[b]] + avg[0];
        float diff = pred - ratings[b];
        s_p[wv] = diff * diff;
    }
    __syncthreads();
    if (threadIdx.x == 0)
        atomicAdd(sse_acc, s_p[0] + s_p[1] + s_p[2] + s_p[3]);
}

__global__ void finalize_k(const float* __restrict__ acc, float* __restrict__ out)
{
    out[0] = acc[2] / (float)BATCH
           + LAM_F * (acc[0] / (float)((double)U_NUM * 64.0))
           + LAM_F * (acc[1] / (float)((double)I_NUM * 64.0));
}

// ---------------------------------------------------------------------------

extern "C" void kernel_launch(void* const* d_in, const int* in_sizes, int n_in,
                              void* d_out, int out_size, void* d_ws, size_t ws_size,
                              hipStream_t stream)
{
    const int*   ui_rows = (const int*)d_in[0];
    const int*   ui_cols = (const int*)d_in[1];
    const float* ui_vals = (const float*)d_in[2];
    const float* iu_vals = (const float*)d_in[3];
    const float* d_i     = (const float*)d_in[4];
    const float* d_j     = (const float*)d_in[5];
    const float* eu      = (const float*)d_in[6];
    const float* ei      = (const float*)d_in[7];
    const float* add_w   = (const float*)d_in[8];
    const float* fw1     = (const float*)d_in[9];
    const float* fb1     = (const float*)d_in[10];
    const float* fw2     = (const float*)d_in[11];
    const float* fb2     = (const float*)d_in[12];
    const float* ub      = (const float*)d_in[13];
    const float* ib      = (const float*)d_in[14];
    const float* avg     = (const float*)d_in[15];
    const int*   user0   = (const int*)d_in[16];
    const int*   item0   = (const int*)d_in[17];
    const float* ratings = (const float*)d_in[18];

    const size_t U64 = (size_t)U_NUM * DDIM;
    const size_t I64 = (size_t)I_NUM * DDIM;

    // ---- CSR-path layout (311 MB) ----
    // g1u (later overwritten in-place with combined gcn_u), g1i, gcnI
    float* g1u  = (float*)d_ws;             // U64
    float* g1i  = g1u + U64;                // I64
    float* gcnI = g1i + I64;                // I64
    float* cu_val = gcnI + I64;             // NNZ
    int*   cu_col = (int*)(cu_val + NNZ_N); // NNZ
    float* ci_val = (float*)(cu_col + NNZ_N);
    int*   ci_row = (int*)(ci_val + NNZ_N);
    int*   meta   = (int*)(ci_row + NNZ_N);
    int*   ptr_u  = meta;                   // U+1
    int*   ptr_i  = ptr_u + (U_NUM + 1);    // I+1
    int*   cur_u  = ptr_i + (I_NUM + 1);    // U
    int*   cur_i  = cur_u + U_NUM;          // I
    int*   bsumU  = cur_i + I_NUM;          // 512
    int*   bsumI  = bsumU + 512;            // 512
    float* accU   = (float*)(bsumI + 512);  // ACC_SLOTS
    float* accI   = accU + ACC_SLOTS;       // ACC_SLOTS
    float* sse    = accI + ACC_SLOTS;       // 4
    size_t meta_ints = (size_t)(U_NUM + 1) + (I_NUM + 1) + U_NUM + I_NUM
                     + 1024 + 2 * ACC_SLOTS + 4;
    size_t needed = ((char*)(meta + meta_ints)) - (char*)d_ws;

    dim3 blk(256);

    if (ws_size >= needed) {
        // ---- CSR path ----
        hipMemsetAsync(meta, 0, meta_ints * sizeof(int), stream);

        int eg = (NNZ_N + 255) / 256;
        hist_k<<<eg, blk, 0, stream>>>(ui_rows, ui_cols, ptr_u, ptr_i, NNZ_N);

        int nU = U_NUM + 1, nI = I_NUM + 1;
        int nbU = (nU + 1023) / 1024, nbI = (nI + 1023) / 1024;
        scan1_k<<<nbU, blk, 0, stream>>>(ptr_u, nU, bsumU);
        scan2_k<<<1, 512, 0, stream>>>(bsumU, nbU);
        scan3_k<<<nbU, blk, 0, stream>>>(ptr_u, nU, bsumU);
        scan1_k<<<nbI, blk, 0, stream>>>(ptr_i, nI, bsumI);
        scan2_k<<<1, 512, 0, stream>>>(bsumI, nbI);
        scan3_k<<<nbI, blk, 0, stream>>>(ptr_i, nI, bsumI);

        scatter_k<<<eg, blk, 0, stream>>>(ui_rows, ui_cols, ui_vals, iu_vals,
                                          ptr_u, ptr_i, cur_u, cur_i,
                                          cu_col, cu_val, ci_row, ci_val, NNZ_N);

        int gu = (U_NUM + 3) / 4, gi = (I_NUM + 3) / 4;
        // layer 1
        spmm_csr_k<0><<<gu, blk, 0, stream>>>(ptr_u, cu_col, cu_val, ei, eu, d_i,
                                              g1u, U_NUM, nullptr, nullptr, nullptr);
        spmm_csr_k<0><<<gi, blk, 0, stream>>>(ptr_i, ci_row, ci_val, eu, ei, d_j,
                                              g1i, I_NUM, nullptr, nullptr, nullptr);
        // layer 2 + combine + fused L2:
        // gcn_i first (reads g1u as x, g1i as base) -> fresh buffer
        spmm_csr_k<1><<<gi, blk, 0, stream>>>(ptr_i, ci_row, ci_val, g1u, g1i, d_j,
                                              gcnI, I_NUM, ei, add_w, accI);
        // gcn_u in-place over g1u (reads g1i as x, g1u as base)
        spmm_csr_k<1><<<gu, blk, 0, stream>>>(ptr_u, cu_col, cu_val, g1i, g1u, d_i,
                                              g1u, U_NUM, eu, add_w, accU);

        batch_mlp2_k<<<1024, blk, 0, stream>>>(user0, item0, g1u, gcnI,
                                               fw1, fb1, fw2, fb2, ub, ib, avg,
                                               ratings, sse);
        finalize2_k<<<1, blk, 0, stream>>>(accU, accI, sse, (float*)d_out);
    } else {
        // ---- fallback: round-1 atomic path (needs 334 MB) ----
        float* f_g1u = (float*)d_ws;
        float* f_g2u = f_g1u + U64;
        float* f_g1i = f_g2u + U64;
        float* f_g2i = f_g1i + I64;
        float* acc   = f_g2i + I64;
        hipMemsetAsync(d_ws, 0, (2 * U64 + 2 * I64 + 8) * sizeof(float), stream);

        int spmm_grid = (NNZ_N + 3) / 4;
        spmm_atomic_k<<<spmm_grid, blk, 0, stream>>>(ui_rows, ui_cols, ui_vals, ei, f_g1u, NNZ_N);
        spmm_atomic_k<<<spmm_grid, blk, 0, stream>>>(ui_cols, ui_rows, iu_vals, eu, f_g1i, NNZ_N);
        relu_resid_k<<<(U_NUM * 16 + 255) / 256, blk, 0, stream>>>(f_g1u, eu, d_i, (size_t)U_NUM * 16);
        relu_resid_k<<<(I_NUM * 16 + 255) / 256, blk, 0, stream>>>(f_g1i, ei, d_j, (size_t)I_NUM * 16);
        spmm_atomic_k<<<spmm_grid, blk, 0, stream>>>(ui_rows, ui_cols, ui_vals, f_g1i, f_g2u, NNZ_N);
        spmm_atomic_k<<<spmm_grid, blk, 0, stream>>>(ui_cols, ui_rows, iu_vals, f_g1u, f_g2i, NNZ_N);
        relu_resid_k<<<(U_NUM * 16 + 255) / 256, blk, 0, stream>>>(f_g2u, f_g1u, d_i, (size_t)U_NUM * 16);
        relu_resid_k<<<(I_NUM * 16 + 255) / 256, blk, 0, stream>>>(f_g2i, f_g1i, d_j, (size_t)I_NUM * 16);
        l2_reduce_k<<<2048, blk, 0, stream>>>(eu, f_g1u, f_g2u, add_w, U64, acc + 0);
        l2_reduce_k<<<2048, blk, 0, stream>>>(ei, f_g1i, f_g2i, add_w, I64, acc + 1);
        batch_mlp_k<<<BATCH / 4, blk, 0, stream>>>(user0, item0, eu, f_g1u, f_g2u, ei, f_g1i, f_g2i,
                                                   add_w, fw1, fb1, fw2, fb2, ub, ib, avg,
                                                   ratings, acc + 2);
        finalize_k<<<1, 1, 0, stream>>>(acc, (float*)d_out);
    }
}